// Round 1
// baseline (3035.542 us; speedup 1.0000x reference)
//
#include <hip/hip_runtime.h>

typedef _Float16 f16;
typedef _Float16 f16x8 __attribute__((ext_vector_type(8)));
typedef _Float16 f16x4 __attribute__((ext_vector_type(4)));
typedef float    f32x4 __attribute__((ext_vector_type(4)));

#define TPB 256

// ---------------------------------------------------------------------------
// Prologue: fused normalize -> per-channel pixel permutation -> space_to_depth
// Output layout: A0[p][c] fp16, p = b*1024 + h2*32 + w2 (8192 px), c = 0..191
// ---------------------------------------------------------------------------
__global__ __launch_bounds__(TPB) void prologue_k(
    const float* __restrict__ x, const float* __restrict__ mu,
    const float* __restrict__ sigma, const int* __restrict__ perm,
    f16* __restrict__ A0)
{
    int gid = blockIdx.x * TPB + threadIdx.x;
    if (gid >= 8192 * 192) return;
    int c = gid % 192;
    int p = gid / 192;
    int b  = p >> 10;
    int h2 = (p >> 5) & 31;
    int w2 = p & 31;
    int cc = c >> 6;
    int bh = (c >> 3) & 7;
    int bw = c & 7;
    int j   = (h2 * 8 + bh) * 256 + (w2 * 8 + bw);   // flat index pre-s2d
    int src = perm[cc * 65536 + j];                   // gather index
    float v = (x[(b * 3 + cc) * 65536 + src] - mu[cc]) / sigma[cc];
    A0[gid] = (f16)v;
}

// ---------------------------------------------------------------------------
// Weight conversion: w_flat fp32 [oc][ic][3][3] -> fp16 [tap][oc][ic] per conv
// grid.y = conv index (0..191)
// ---------------------------------------------------------------------------
__global__ __launch_bounds__(TPB) void wconv_k(const float* __restrict__ wf,
                                               f16* __restrict__ wh)
{
    int c   = blockIdx.y;
    int idx = blockIdx.x * TPB + threadIdx.x;
    int s   = c % 6;
    int s3  = s % 3;
    int oc  = (s3 == 2) ? 96 : 128;
    int ic  = (s3 == 0) ? 96 : 128;
    int wo  = (s3 == 0 ? 0 : (s3 == 1 ? 110592 : 258048)) + (s >= 3 ? 368640 : 0);
    int ocic = oc * ic;
    int n    = ocic * 9;
    if (idx >= n) return;
    size_t base = (size_t)(c / 6) * 737280 + wo;
    int tap = idx / ocic;
    int r   = idx - tap * ocic;
    int o   = r / ic;
    int i   = r - o * ic;
    wh[base + idx] = (f16)wf[base + (size_t)o * ic * 9 + (size_t)i * 9 + tap];
}

// m fp32 -> fp16 (scale folded into mix epilogue, not here)
__global__ __launch_bounds__(TPB) void mconv_k(const float* __restrict__ mf,
                                               f16* __restrict__ mh, int n)
{
    int i = blockIdx.x * TPB + threadIdx.x;
    if (i < n) mh[i] = (f16)mf[i];
}

// biases fp32, pre-scaled by 2^-block (704 biases per block)
__global__ __launch_bounds__(TPB) void bconv_k(const float* __restrict__ bf,
                                               float* __restrict__ bs, int n)
{
    int i = blockIdx.x * TPB + threadIdx.x;
    if (i < n) bs[i] = ldexpf(bf[i], -(i / 704));
}

// ---------------------------------------------------------------------------
// Conv / 1x1-mix kernel (implicit GEMM over 9 taps, fp16 MFMA 16x16x32).
//   grid.x = 64 pixel tiles (4 rows of one image each), grid.y = OC/32.
//   Block 256 = 4 waves; wave w owns image row r0+w (32 px) x 32 oc.
//   X tile (+halo for 3x3) staged in LDS as [row][c8][w][8ch];
//   W staged per tap as [c8][oc_local][8ch].
//   Epilogue: *scale, +bias, ReLU, optional accumulate, fp16 or final fp32.
// ---------------------------------------------------------------------------
template<int IC, int OC, int TAPS, bool RELU, bool ACCUM, bool OUT32>
__global__ __launch_bounds__(TPB) void conv_k(
    const f16* __restrict__ Xin, int ICS,
    const f16* __restrict__ W,  const float* __restrict__ bias,
    f16* __restrict__ Out, int OCS, float* __restrict__ Out32, float scale)
{
    constexpr int R    = 4;
    constexpr int NC8  = IC / 8;
    constexpr int PAD  = (TAPS == 9) ? 1 : 0;
    constexpr int ROWS = R + 2 * PAD;
    constexpr int WW   = 32 + 2 * PAD;

    extern __shared__ f16 lds[];
    f16* Alds = lds + ROWS * NC8 * WW * 8;

    const int tid  = threadIdx.x;
    const int tile = blockIdx.x;
    const int img  = tile >> 3;
    const int r0   = (tile & 7) * R;
    const int oc0  = blockIdx.y * 32;

    // ---- stage X tile (+halo) ----
    for (int i = tid; i < ROWS * WW * NC8; i += TPB) {
        int c8  = i % NC8;
        int rem = i / NC8;
        int wv  = rem % WW;
        int ri  = rem / WW;
        int row = r0 - PAD + ri;
        int wc  = wv - PAD;
        f16x8 v = {};
        if ((unsigned)row < 32u && (unsigned)wc < 32u) {
            int p = img * 1024 + row * 32 + wc;
            v = *(const f16x8*)&Xin[(size_t)p * ICS + c8 * 8];
        }
        *(f16x8*)&lds[((ri * NC8 + c8) * WW + wv) * 8] = v;
    }

    const int lane = tid & 63;
    const int wave = tid >> 6;
    const int lq   = lane >> 4;   // quadrant 0..3
    const int ln   = lane & 15;

    f32x4 acc[2][2] = {};

    for (int tap = 0; tap < TAPS; ++tap) {
        __syncthreads();  // X staged (tap0) / Alds no longer in use (tap>0)
        // ---- stage W[tap] slice: [c8][oc_local][8] ----
        for (int i = tid; i < 32 * NC8; i += TPB) {
            int o  = i & 31;
            int c8 = i >> 5;
            *(f16x8*)&Alds[(c8 * 32 + o) * 8] =
                *(const f16x8*)&W[((size_t)tap * OC + oc0 + o) * IC + c8 * 8];
        }
        __syncthreads();

        const int dy = (TAPS == 9) ? tap / 3 - 1 : 0;
        const int dx = (TAPS == 9) ? tap % 3 - 1 : 0;
        const int bb = ((wave + PAD + dy) * NC8 * WW + (ln + dx + PAD)) * 8;

#pragma unroll
        for (int kc = 0; kc < IC / 32; ++kc) {
            f16x8 a0 = *(const f16x8*)&Alds[((kc * 4 + lq) * 32 + ln) * 8];
            f16x8 a1 = *(const f16x8*)&Alds[((kc * 4 + lq) * 32 + 16 + ln) * 8];
            f16x8 b0 = *(const f16x8*)&lds[bb + (kc * 4 + lq) * WW * 8];
            f16x8 b1 = *(const f16x8*)&lds[bb + (kc * 4 + lq) * WW * 8 + 128];
            acc[0][0] = __builtin_amdgcn_mfma_f32_16x16x32_f16(a0, b0, acc[0][0], 0, 0, 0);
            acc[1][0] = __builtin_amdgcn_mfma_f32_16x16x32_f16(a1, b0, acc[1][0], 0, 0, 0);
            acc[0][1] = __builtin_amdgcn_mfma_f32_16x16x32_f16(a0, b1, acc[0][1], 0, 0, 0);
            acc[1][1] = __builtin_amdgcn_mfma_f32_16x16x32_f16(a1, b1, acc[1][1], 0, 0, 0);
        }
    }

    // ---- epilogue ----
    const int prow = r0 + wave;
#pragma unroll
    for (int mm = 0; mm < 2; ++mm) {
#pragma unroll
        for (int nn = 0; nn < 2; ++nn) {
            int oc = oc0 + mm * 16 + lq * 4;
            int p  = img * 1024 + prow * 32 + nn * 16 + ln;
            float b0 = 0.f, b1 = 0.f, b2 = 0.f, b3 = 0.f;
            if (TAPS == 9) {
                float4 bv = *(const float4*)&bias[oc];
                b0 = bv.x; b1 = bv.y; b2 = bv.z; b3 = bv.w;
            }
            float v0 = acc[mm][nn][0] * scale + b0;
            float v1 = acc[mm][nn][1] * scale + b1;
            float v2 = acc[mm][nn][2] * scale + b2;
            float v3 = acc[mm][nn][3] * scale + b3;
            if (RELU) {
                v0 = fmaxf(v0, 0.f); v1 = fmaxf(v1, 0.f);
                v2 = fmaxf(v2, 0.f); v3 = fmaxf(v3, 0.f);
            }
            if (OUT32) {
                size_t ob = (size_t)(img * 192 + oc) * 1024 + prow * 32 + nn * 16 + ln;
                Out32[ob]          = v0;
                Out32[ob + 1024]   = v1;
                Out32[ob + 2048]   = v2;
                Out32[ob + 3072]   = v3;
            } else {
                f16* op = &Out[(size_t)p * OCS + oc];
                if (ACCUM) {
                    f16x4 old = *(const f16x4*)op;
                    v0 += (float)old[0]; v1 += (float)old[1];
                    v2 += (float)old[2]; v3 += (float)old[3];
                }
                f16x4 hv;
                hv[0] = (f16)v0; hv[1] = (f16)v1; hv[2] = (f16)v2; hv[3] = (f16)v3;
                *(f16x4*)op = hv;
            }
        }
    }
}

// ---------------------------------------------------------------------------
extern "C" void kernel_launch(void* const* d_in, const int* in_sizes, int n_in,
                              void* d_out, int out_size, void* d_ws, size_t ws_size,
                              hipStream_t stream)
{
    const float* x     = (const float*)d_in[0];
    const float* mu    = (const float*)d_in[1];
    const float* sigma = (const float*)d_in[2];
    const float* wf    = (const float*)d_in[3];
    const float* bf    = (const float*)d_in[4];
    const float* mf    = (const float*)d_in[5];
    const int*   perm  = (const int*)d_in[6];
    float*       out   = (float*)d_out;

    char* ws = (char*)d_ws;
    f16*   WH = (f16*)(ws);                       // 23,592,960 f16 = 47,185,920 B
    f16*   MH = (f16*)(ws + 47185920);            //  1,179,648 f16 =  2,359,296 B
    float* BS = (float*)(ws + 49545216);          //     22,528 f32 =     90,112 B
    f16*   XA = (f16*)(ws + 49635328);            //  8192*192 f16  =  3,145,728 B
    f16*   XB = (f16*)(ws + 52781056);
    f16*   H1 = (f16*)(ws + 55926784);            //  8192*128 f16  =  2,097,152 B
    f16*   H2 = (f16*)(ws + 58023936);

    // conversions + prologue
    wconv_k<<<dim3(576, 192), TPB, 0, stream>>>(wf, WH);
    mconv_k<<<dim3(4608), TPB, 0, stream>>>(mf, MH, 1179648);
    bconv_k<<<dim3(88),   TPB, 0, stream>>>(bf, BS, 22528);
    prologue_k<<<dim3(6144), TPB, 0, stream>>>(x, mu, sigma, perm, XA);

    static const int wo6[6] = {0, 110592, 258048, 368640, 479232, 626688};
    static const int bo6[6] = {0, 128, 256, 352, 480, 608};

    constexpr int LDS96  = (6 * 12 * 34 * 8 + 96 * 32) * 2;   // 45,312 B
    constexpr int LDS128 = (6 * 16 * 34 * 8 + 128 * 32) * 2;  // 60,416 B
    constexpr int LDS192 = (4 * 24 * 32 * 8 + 192 * 32) * 2;  // 61,440 B

    f16* cur = XA;
    f16* nxt = XB;
    for (int blk = 0; blk < 32; ++blk) {
        int c = blk * 6;
        size_t w0 = (size_t)blk * 737280;
        size_t b0 = (size_t)blk * 704;
        // round 1: chain(half1) -> accumulate into half0
        conv_k<96, 128, 9, true,  false, false><<<dim3(64, 4), TPB, LDS96, stream>>>(
            cur + 96, 192, WH + w0 + wo6[0], BS + b0 + bo6[0], H1, 128, nullptr, 1.0f);
        conv_k<128, 128, 9, true,  false, false><<<dim3(64, 4), TPB, LDS128, stream>>>(
            H1, 128, WH + w0 + wo6[1], BS + b0 + bo6[1], H2, 128, nullptr, 1.0f);
        conv_k<128, 96, 9, false, true,  false><<<dim3(64, 3), TPB, LDS128, stream>>>(
            H2, 128, WH + w0 + wo6[2], BS + b0 + bo6[2], cur, 192, nullptr, 1.0f);
        // round 2: chain(half0) -> accumulate into half1
        conv_k<96, 128, 9, true,  false, false><<<dim3(64, 4), TPB, LDS96, stream>>>(
            cur, 192, WH + w0 + wo6[3], BS + b0 + bo6[3], H1, 128, nullptr, 1.0f);
        conv_k<128, 128, 9, true,  false, false><<<dim3(64, 4), TPB, LDS128, stream>>>(
            H1, 128, WH + w0 + wo6[4], BS + b0 + bo6[4], H2, 128, nullptr, 1.0f);
        conv_k<128, 96, 9, false, true,  false><<<dim3(64, 3), TPB, LDS128, stream>>>(
            H2, 128, WH + w0 + wo6[5], BS + b0 + bo6[5], cur + 96, 192, nullptr, 1.0f);
        // mix: y = M @ x, with 2^-1 rescale (or 2^31 un-scale + fp32 out on last)
        if (blk < 31) {
            conv_k<192, 192, 1, false, false, false><<<dim3(64, 6), TPB, LDS192, stream>>>(
                cur, 192, MH + (size_t)blk * 36864, nullptr, nxt, 192, nullptr, 0.5f);
        } else {
            conv_k<192, 192, 1, false, false, true><<<dim3(64, 6), TPB, LDS192, stream>>>(
                cur, 192, MH + (size_t)blk * 36864, nullptr, nullptr, 192, out,
                2147483648.0f /* 2^31 */);
        }
        f16* t = cur; cur = nxt; nxt = t;
    }
}